// Round 1
// 659.229 us; speedup vs baseline: 1.0411x; 1.0411x over previous
//
#include <hip/hip_runtime.h>
#include <hip/hip_bf16.h>

// Problem: out[i,m] = sum_{j,k,l} G[j,k] * x[i,k,l] * (v-w)[j,l,m]
// i(BATCH)=256, j(NEURONS)=1024, k(N_FEAT)=1024, l(IN_DIM)=256, m(OUT_DIM)=128
//
// Factorization (86 GFLOP total, minimal):
//   T[k,l,m] = sum_j G[j,k] * (v-w)[j,l,m]        (GEMM 1024 x 32768 x K=1024)
//   out[i,m] = sum_{k,l} x[i,k,l] * T[k,l,m]      (GEMM 256 x 128 x K=262144, split-K)
//
// Layouts (all GEMM operands K-contiguous for global_load_lds + ds_read_b128):
//   Gt[k*1024 + j]                      bf16, A of stage 1
//   Dt[(m*256+l)*1024 + j]              bf16, B of stage 1 (n' = m*256+l)
//   Tt[m*262144 + k*256 + l]            bf16, stage-1 out = B^T of stage 2 (m-major, kl=k*256+l)
//   x natural [i][k*256+l] fp32 -> cvt bf16 in-register (A of stage 2)
//
// This version: counted-vmcnt software pipelines (raw s_barrier, never vmcnt(0)
// mid-loop), 256^2 tile for gemm1 with LDS-repacked coalesced epilogue,
// split-K x2 + 4-deep Ts pipeline + async x staging for gemm2.

typedef __attribute__((ext_vector_type(8))) short bf16x8;
typedef __attribute__((ext_vector_type(4))) float f32x4;

#define AS1C(p) ((const __attribute__((address_space(1))) void*)(p))
#define AS3(p)  ((__attribute__((address_space(3))) void*)(p))
#define FENCE() asm volatile("" ::: "memory")

__device__ __forceinline__ unsigned short f2bf(float f) {
    unsigned u = __float_as_uint(f);
    unsigned r = u + 0x7fffu + ((u >> 16) & 1u);   // round-to-nearest-even
    return (unsigned short)(r >> 16);
}

// ---------------- prep: Gt[k][j] = bf16(G[j][k]) ----------------
// grid (32,32), block (32,8)
__global__ void prep_G(const float* __restrict__ G, unsigned short* __restrict__ Gt) {
    __shared__ float tile[32][33];
    int k0 = blockIdx.x * 32, j0 = blockIdx.y * 32;
    int tx = threadIdx.x, ty = threadIdx.y;
    #pragma unroll
    for (int r = 0; r < 32; r += 8)
        tile[ty + r][tx] = G[(size_t)(j0 + ty + r) * 1024 + k0 + tx];   // tile[jloc][kloc]
    __syncthreads();
    #pragma unroll
    for (int r = 0; r < 32; r += 8)
        Gt[(size_t)(k0 + ty + r) * 1024 + j0 + tx] = f2bf(tile[tx][ty + r]);
}

// ---------------- prep: Dt[(m*256+l)*1024 + j] = bf16(v-w) ----------------
// grid (32, 256): bx = j-tile (32 wide), by = l.  block 256.
__global__ void prep_D(const float* __restrict__ v, const float* __restrict__ w,
                       unsigned short* __restrict__ Dt) {
    __shared__ unsigned short tile[32][132];   // [j][m], padded
    int j0 = blockIdx.x * 32;
    int l  = blockIdx.y;
    int t  = threadIdx.x;
    #pragma unroll
    for (int it = 0; it < 16; ++it) {
        int idx = it * 256 + t;
        int j = idx >> 7, m = idx & 127;
        size_t g = (size_t)(j0 + j) * 32768 + (size_t)l * 128 + m;
        tile[j][m] = f2bf(v[g] - w[g]);
    }
    __syncthreads();
    int m = t >> 1, half = t & 1;
    unsigned short vals[16];
    #pragma unroll
    for (int q = 0; q < 16; ++q) vals[q] = tile[half * 16 + q][m];
    size_t dst = ((size_t)m * 256 + l) * 1024 + j0 + half * 16;
    *(uint4*)(Dt + dst)     = *(uint4*)(vals);
    *(uint4*)(Dt + dst + 8) = *(uint4*)(vals + 8);
}

// ---------------- stage 1: Tt = Gt (1024x1024) @ Dt^T (1024x32768) ----------------
// M=1024(k) N=32768(n') K=1024(j).  256x256 tile, BK=32, 8 waves, acc 8x4 /wave.
// 3-slot LDS pipeline (depth-2 prefetch, vmcnt(4) steady state, 1 barrier/iter).
// grid 512 (1D, XCD-grouped), block 512.
__global__ __launch_bounds__(512, 2) void gemm1(const unsigned short* __restrict__ Gt,
                                                const unsigned short* __restrict__ Dt,
                                                unsigned short* __restrict__ Tt) {
    // staging: 3 slots x (A 8192 + B 8192) shorts = 49152; epilogue repack: 256x256 = 65536
    __shared__ __align__(16) unsigned short sm[65536];   // 128 KiB
    int tid = threadIdx.x, wv = tid >> 6, lane = tid & 63;
    // XCD-grouped swizzle: siblings sharing a Dt panel (same by) -> same XCD.
    int n   = blockIdx.x;                       // 0..511
    int by  = ((n >> 5) << 3) + (n & 7);        // 0..127
    int bx  = (n >> 3) & 3;                     // 0..3
    int k0 = bx * 256, n0 = by * 256;
    int quad = lane >> 4, l15 = lane & 15;
    int wr = (wv >> 2) * 128, wc = (wv & 3) * 64;
    int ldrow = lane >> 2, ldcol = (lane & 3) * 8;
    const unsigned short* gA = Gt + (size_t)k0 * 1024;
    const unsigned short* gB = Dt + (size_t)n0 * 1024;

    f32x4 acc[8][4] = {};

    auto stage = [&](int slot, int jt) {
        int j0 = jt * 32;
        unsigned short* As = sm + slot * 16384;
        unsigned short* Bs = As + 8192;
        #pragma unroll
        for (int i = 0; i < 2; ++i) {
            int r = (wv * 2 + i) * 16;   // wave-uniform LDS base; lanes scatter +lane*16B
            __builtin_amdgcn_global_load_lds(
                AS1C(gA + (size_t)(r + ldrow) * 1024 + j0 + ldcol), AS3(As + r * 32), 16, 0, 0);
            __builtin_amdgcn_global_load_lds(
                AS1C(gB + (size_t)(r + ldrow) * 1024 + j0 + ldcol), AS3(Bs + r * 32), 16, 0, 0);
        }
    };

    stage(0, 0);
    stage(1, 1);
    int sR = 0;
    for (int kt = 0; kt < 32; ++kt) {
        // tile kt landed (only tile kt+1's 4 loads may remain in flight)
        if (kt + 1 < 32) asm volatile("s_waitcnt vmcnt(4)" ::: "memory");
        else             asm volatile("s_waitcnt vmcnt(0)" ::: "memory");
        __builtin_amdgcn_s_barrier();
        FENCE();
        if (kt + 2 < 32) {
            int sW = sR + 2; if (sW >= 3) sW -= 3;
            stage(sW, kt + 2);           // slot retired by barrier above; readers hold kt, kt+1
        }
        const unsigned short* As = sm + sR * 16384;
        const unsigned short* Bs = As + 8192;
        bf16x8 a[8], b[4];
        #pragma unroll
        for (int rt = 0; rt < 8; ++rt)
            a[rt] = *(const bf16x8*)(As + (wr + rt * 16 + l15) * 32 + quad * 8);
        #pragma unroll
        for (int ct = 0; ct < 4; ++ct)
            b[ct] = *(const bf16x8*)(Bs + (wc + ct * 16 + l15) * 32 + quad * 8);
        __builtin_amdgcn_s_setprio(1);
        #pragma unroll
        for (int rt = 0; rt < 8; ++rt)
            #pragma unroll
            for (int ct = 0; ct < 4; ++ct)
                acc[rt][ct] = __builtin_amdgcn_mfma_f32_16x16x32_bf16(a[rt], b[ct], acc[rt][ct], 0, 0, 0);
        __builtin_amdgcn_s_setprio(0);
        sR = sR + 1; if (sR >= 3) sR = 0;
    }

    // ---- epilogue: repack C[256][256] bf16 via LDS, store coalesced ----
    FENCE();
    __builtin_amdgcn_s_barrier();    // all waves done reading staging slots
    FENCE();
    // LDS layout: byte(row,col) = row*512 + ((col*2) ^ (((row>>2)&3)<<5))
    // quad-XOR spreads the 4 quads across all 32 banks (2 lanes/bank = free).
    #pragma unroll
    for (int rt = 0; rt < 8; ++rt)
        #pragma unroll
        for (int ct = 0; ct < 4; ++ct)
            #pragma unroll
            for (int r = 0; r < 4; ++r) {
                int row = wr + rt * 16 + quad * 4 + r;
                int col = wc + ct * 16 + l15;
                int byt = row * 512 + ((col * 2) ^ (((row >> 2) & 3) << 5));
                *(unsigned short*)((char*)sm + byt) = f2bf(acc[rt][ct][r]);
            }
    asm volatile("s_waitcnt lgkmcnt(0)" ::: "memory");
    __builtin_amdgcn_s_barrier();
    FENCE();
    // block output = Tt[mm][k0..k0+255][0..255]: one contiguous 128 KiB region
    int mm = n0 >> 8;
    size_t base = (size_t)mm * 262144 + (size_t)k0 * 256;
    #pragma unroll
    for (int u = 0; u < 16; ++u) {
        int c = u * 512 + tid;           // 16B chunk index; per wave-instr: 1 KiB contiguous
        int row = c >> 5, col16 = c & 31;
        int byt = row * 512 + ((col16 * 16) ^ (((row >> 2) & 3) << 5));
        *(uint4*)(Tt + base + (size_t)c * 8) = *(const uint4*)((const char*)sm + byt);
    }
}

// ---------------- stage 2: out(256x128) = x(256x262144) @ Tt^T, split-K ----------------
// 1024 blocks (XCD-grouped), 64-row i-tile x 1024-wide K-chunk, block 256.
// 4-slot Ts pipeline (depth-2, vmcnt(2)) + async x reg-staging (T14). atomicAdd fp32.
__global__ __launch_bounds__(256, 4) void gemm2(const float* __restrict__ x,
                                                const unsigned short* __restrict__ Tt,
                                                float* __restrict__ out) {
    // Ts slots: 4 x 4096 shorts; Xs: 2 x 2048 shorts  -> 40 KiB total
    __shared__ __align__(16) unsigned short sm[4 * 4096 + 2 * 2048];
    int tid = threadIdx.x, wv = tid >> 6, lane = tid & 63;
    int n   = blockIdx.x;                        // 0..1023
    int by  = ((n >> 5) << 3) + (n & 7);         // 0..255  (K-chunk)
    int bx  = (n >> 3) & 3;                      // 0..3    (i-tile)
    int i0 = bx * 64;
    size_t kl0 = (size_t)by * 1024;
    int ldrow = lane >> 2, ldcol = (lane & 3) * 8;
    int wr = (wv >> 1) * 32, wc = (wv & 1) * 64;
    int quad = lane >> 4, l15 = lane & 15;

    f32x4 acc[2][4] = {};
    float4 xv[2];

    auto stageT = [&](int slot, int t) {
        size_t kk = kl0 + (size_t)t * 32;
        unsigned short* Ts = sm + slot * 4096;
        #pragma unroll
        for (int i = 0; i < 2; ++i) {
            int r = (wv * 2 + i) * 16;
            __builtin_amdgcn_global_load_lds(
                AS1C(Tt + (size_t)(r + ldrow) * 262144 + kk + ldcol), AS3(Ts + r * 32), 16, 0, 0);
        }
    };
    auto loadX = [&](int t) {
        size_t kk = kl0 + (size_t)t * 32;
        #pragma unroll
        for (int i = 0; i < 2; ++i) {
            int f = tid + i * 256;
            int r = f >> 3, c = (f & 7) * 4;
            xv[i] = *(const float4*)(x + (size_t)(i0 + r) * 262144 + kk + c);
        }
    };

    loadX(0);            // x loads FIRST (vmcnt counting relies on this order)
    stageT(0, 0);
    stageT(1, 1);

    for (int kt = 0; kt < 32; ++kt) {
        // x(kt) in regs + Ts(kt) in LDS; only Ts(kt+1)'s 2 loads may remain in flight
        if (kt + 1 < 32) asm volatile("s_waitcnt vmcnt(2)" ::: "memory");
        else             asm volatile("s_waitcnt vmcnt(0)" ::: "memory");
        // write x(kt) into Xs[kt&1] (last read two barriers ago -> safe)
        unsigned short* Xw = sm + 16384 + (kt & 1) * 2048;
        #pragma unroll
        for (int i = 0; i < 2; ++i) {
            int f = tid + i * 256;
            int r = f >> 3, c = (f & 7) * 4;
            unsigned short h[4] = {f2bf(xv[i].x), f2bf(xv[i].y), f2bf(xv[i].z), f2bf(xv[i].w)};
            *(uint2*)(Xw + r * 32 + c) = *(uint2*)h;
        }
        asm volatile("s_waitcnt lgkmcnt(0)" ::: "memory");
        __builtin_amdgcn_s_barrier();
        FENCE();
        if (kt + 1 < 32) loadX(kt + 1);                       // issue early, hide under MFMA
        if (kt + 2 < 32) stageT((kt + 2) & 3, kt + 2);        // readers hold kt, kt+1 -> safe
        const unsigned short* Xs = sm + 16384 + (kt & 1) * 2048;
        const unsigned short* Ts = sm + (kt & 3) * 4096;
        bf16x8 a[2], b[4];
        #pragma unroll
        for (int rt = 0; rt < 2; ++rt)
            a[rt] = *(const bf16x8*)(Xs + (wr + rt * 16 + l15) * 32 + quad * 8);
        #pragma unroll
        for (int ct = 0; ct < 4; ++ct)
            b[ct] = *(const bf16x8*)(Ts + (wc + ct * 16 + l15) * 32 + quad * 8);
        #pragma unroll
        for (int rt = 0; rt < 2; ++rt)
            #pragma unroll
            for (int ct = 0; ct < 4; ++ct)
                acc[rt][ct] = __builtin_amdgcn_mfma_f32_16x16x32_bf16(a[rt], b[ct], acc[rt][ct], 0, 0, 0);
    }
    #pragma unroll
    for (int rt = 0; rt < 2; ++rt)
        #pragma unroll
        for (int ct = 0; ct < 4; ++ct)
            #pragma unroll
            for (int r = 0; r < 4; ++r) {
                int i  = i0 + wr + rt * 16 + quad * 4 + r;
                int mo = wc + ct * 16 + l15;
                atomicAdd(&out[(size_t)i * 128 + mo], acc[rt][ct][r]);
            }
}

extern "C" void kernel_launch(void* const* d_in, const int* in_sizes, int n_in,
                              void* d_out, int out_size, void* d_ws, size_t ws_size,
                              hipStream_t stream) {
    const float* x = (const float*)d_in[0];   // 256*1024*256
    const float* G = (const float*)d_in[1];   // 1024*1024
    const float* v = (const float*)d_in[2];   // 1024*256*128
    const float* w = (const float*)d_in[3];   // 1024*256*128
    float* out = (float*)d_out;               // 256*128 fp32

    char* ws = (char*)d_ws;
    unsigned short* Dt = (unsigned short*)(ws);                  // 67,108,864 B
    unsigned short* Tt = (unsigned short*)(ws + 67108864);       // 67,108,864 B
    unsigned short* Gt = (unsigned short*)(ws + 134217728);      //  2,097,152 B

    hipMemsetAsync(d_out, 0, (size_t)256 * 128 * sizeof(float), stream);
    prep_G<<<dim3(32, 32), dim3(32, 8), 0, stream>>>(G, Gt);
    prep_D<<<dim3(32, 256), 256, 0, stream>>>(v, w, Dt);
    gemm1<<<512, 512, 0, stream>>>(Gt, Dt, Tt);
    gemm2<<<1024, 256, 0, stream>>>(x, Tt, out);
}